// Round 11
// baseline (1003.903 us; speedup 1.0000x reference)
//
#include <hip/hip_runtime.h>

#define BB    32
#define CDIM  256
#define TT    2048
#define NE    1024
#define NROWS (BB * TT)          // 65536
#define NELEM (BB * CDIM * TT)   // 16777216

#define BM   64                  // rows per block (was 128; LDS 48KB -> 3 blk/CU)
#define NCH  8                   // code chunks of 128 (all 1024 codes/block)

// screening window (r3/r10-proven value): rows with (2nd best - best) <= FBW
// are re-resolved by the bit-exact fallback scan.  2B ~= 1.32e-4 (exact-gap
// quantization 2*ulp(256) + split/order error); 2.5e-4 gives ~1.9x margin.
#define FBW 2.5e-4f

typedef unsigned short u16;
typedef unsigned int   u32;
typedef __attribute__((ext_vector_type(8))) short s16x8;   // 8 bf16
typedef __attribute__((ext_vector_type(4))) float f32x4;

__device__ __forceinline__ u16 f2bf(float f) {
  u32 u = __float_as_uint(f);
  u += 0x7fffu + ((u >> 16) & 1u);     // RNE; no NaN/overflow in our range
  return (u16)(u >> 16);
}

// ---------------------------------------------------------------------------
// numpy pairwise sum of squares over 128 elements (stride in elements).
// fp contract OFF (numpy squares then adds, no FMA).  EXACT path helpers.
// ---------------------------------------------------------------------------
__device__ __forceinline__ float np_sq_sum128(const float* p, int stride) {
#pragma clang fp contract(off)
  float r[8];
#pragma unroll
  for (int j = 0; j < 8; j++) {
    float v = p[(size_t)j * stride];
    r[j] = v * v;
  }
  for (int i = 8; i < 128; i += 8) {
#pragma unroll
    for (int j = 0; j < 8; j++) {
      float v = p[(size_t)(i + j) * stride];
      float s = v * v;
      r[j] += s;
    }
  }
  return ((r[0] + r[1]) + (r[2] + r[3])) + ((r[4] + r[5]) + (r[6] + r[7]));
}

__global__ __launch_bounds__(256) void e2_kernel(const float* __restrict__ cb,
                                                 float* __restrict__ e2) {
#pragma clang fp contract(off)
  int k = blockIdx.x * 256 + threadIdx.x;
  if (k >= NE) return;
  const float* p = cb + (size_t)k * CDIM;
  float h0 = np_sq_sum128(p, 1);
  float h1 = np_sq_sum128(p + 128, 1);
  e2[k] = h0 + h1;
}

__global__ __launch_bounds__(256) void z2_kernel(const float* __restrict__ z,
                                                 float* __restrict__ z2) {
#pragma clang fp contract(off)
  int n = blockIdx.x * 256 + threadIdx.x;
  if (n >= NROWS) return;
  int b = n >> 11;
  int t = n & (TT - 1);
  const float* p = z + (size_t)b * CDIM * TT + t;
  float h0 = np_sq_sum128(p, TT);
  float h1 = np_sq_sum128(p + (size_t)128 * TT, TT);
  z2[n] = h0 + h1;
}

// cb (1024 x 256) -> cbT (256 x 1024) in d_ws, both sides coalesced
__global__ __launch_bounds__(256) void transpose_cb_kernel(
    const float* __restrict__ cb, float* __restrict__ cbT) {
  __shared__ float tile[32][33];
  int tx = threadIdx.x & 31, ty = threadIdx.x >> 5;
  int n0 = blockIdx.x * 32, c0 = blockIdx.y * 32;
#pragma unroll
  for (int i = 0; i < 4; i++)
    tile[ty + 8 * i][tx] = cb[(size_t)(n0 + ty + 8 * i) * CDIM + c0 + tx];
  __syncthreads();
#pragma unroll
  for (int i = 0; i < 4; i++)
    cbT[(size_t)(c0 + ty + 8 * i) * NE + n0 + tx] = tile[tx][ty + 8 * i];
}

// ---------------------------------------------------------------------------
// cb (1024 x 256) fp32 -> cbhi/cblo bf16 (hi + residual), same [code][k] layout
// ---------------------------------------------------------------------------
__global__ __launch_bounds__(256) void convert_cb_kernel(
    const float* __restrict__ cb, u16* __restrict__ cbhi,
    u16* __restrict__ cblo) {
  int i = blockIdx.x * 256 + threadIdx.x;   // grid 1024 -> 262144 elems
  float v  = cb[i];
  u16  h   = f2bf(v);
  float hf = __uint_as_float((u32)h << 16);
  cbhi[i] = h;
  cblo[i] = f2bf(v - hf);
}

// ---------------------------------------------------------------------------
// z (B, C, T) fp32 -> zhi/zlo bf16, row-major [(b,t)][c]   (tiled transpose)
// ---------------------------------------------------------------------------
__global__ __launch_bounds__(256) void convert_z_kernel(
    const float* __restrict__ z, u16* __restrict__ zhi,
    u16* __restrict__ zlo) {
  __shared__ float tile[32][33];
  int bx = blockIdx.x;              // 32 b * 8 c-tiles * 64 t-tiles = 16384
  int b  = bx >> 9;
  int r  = bx & 511;
  int c0 = (r >> 6) << 5;
  int t0 = (r & 63) << 5;
  int tx = threadIdx.x & 31, ty = threadIdx.x >> 5;
#pragma unroll
  for (int i = 0; i < 4; i++) {
    int c = c0 + ty + 8 * i;
    tile[ty + 8 * i][tx] = z[((size_t)b * CDIM + c) * TT + t0 + tx];
  }
  __syncthreads();
#pragma unroll
  for (int i = 0; i < 4; i++) {
    int tl = ty + 8 * i;
    size_t n = (size_t)b * TT + t0 + tl;
    float v  = tile[tx][tl];
    u16  h   = f2bf(v);
    float hf = __uint_as_float((u32)h << 16);
    zhi[n * CDIM + c0 + tx] = h;
    zlo[n * CDIM + c0 + tx] = f2bf(v - hf);
  }
}

// ---------------------------------------------------------------------------
// Distance screen + argmin: bf16-split MFMA GEMM (numerics identical to the
// r10-passed kernel; BM 128->64 for occupancy: LDS 48KB -> 3 blocks/CU).
// G = zhi*chi + zhi*clo + zlo*chi; screened d = e2[c] - 2G.
// Block: 64 rows x 1024 codes (8 chunks of 128).  4 waves as 2x2
// (wave tile 32 rows x 64 codes, acc 2x4).
// ---------------------------------------------------------------------------
struct StageMem {                       // 48 KiB
  u16 ah[2][64][32];                    // zhi  [plane][row][k]   8 KiB
  u16 al[2][64][32];                    // zlo                    8 KiB
  u16 bh[2][128][32];                   // cbhi [plane][code][k] 16 KiB
  u16 bl[2][128][32];                   // cblo                  16 KiB
};
struct RedMem {
  float rv1[BM][2];
  float rv2[BM][2];
  int   ri1[BM][2];
};

#define GLL(g, l)                                                            \
  __builtin_amdgcn_global_load_lds(                                          \
      (const __attribute__((address_space(1))) void*)(g),                    \
      (__attribute__((address_space(3))) void*)(l), 16, 0, 0)

__global__ __launch_bounds__(256, 3) void dist_argmin_kernel(
    const u16* __restrict__ zhi, const u16* __restrict__ zlo,
    const u16* __restrict__ cbhi, const u16* __restrict__ cblo,
    const float* __restrict__ e2, int* __restrict__ out_idx,
    int* __restrict__ fb_cnt, int* __restrict__ fb_list) {
  __shared__ union SMem {
    StageMem st;
    RedMem   rd;
  } sm;

  const int tid  = threadIdx.x;
  const int lane = tid & 63;
  const int wid  = tid >> 6;
  const int wr   = wid >> 1;            // wave row (0..1): rows wr*32..
  const int wc   = wid & 1;             // wave col (0..1): codes wc*64..
  const int lr   = lane & 15;           // A-row / B-col within 16x16 tile
  const int kg   = lane >> 4;           // k-group (8 k's each)
  const int row0 = blockIdx.x * BM;
  const int sw   = (lr >> 1) & 3;       // frag-read swizzle (row>>1)&3

  const u16* zhiB = zhi + (size_t)row0 * CDIM;
  const u16* zloB = zlo + (size_t)row0 * CDIM;

  float bv1[8], bv2[8];
  int   bi1[8];
#pragma unroll
  for (int i = 0; i < 8; i++) {
    bv1[i] = __builtin_inff(); bv2[i] = __builtin_inff(); bi1[i] = 0;
  }

  for (int ch = 0; ch < NCH; ch++) {
    const int code0 = ch * 128;
    const u16* bhB = cbhi + (size_t)code0 * CDIM;
    const u16* blB = cblo + (size_t)code0 * CDIM;

    f32x4 acc[2][4];
#pragma unroll
    for (int a = 0; a < 2; a++)
#pragma unroll
      for (int b = 0; b < 4; b++) acc[a][b] = (f32x4){0.f, 0.f, 0.f, 0.f};

    for (int ph = 0; ph < 4; ph++) {
      const int kc = ph * 64;
      __syncthreads();
      // z arrays: 512 slots of 16B each; LDS dest linear in slot,
      // global source picks k-quarter q = pos ^ ((row>>1)&3)  (inverse swz)
#pragma unroll
      for (int h = 0; h < 2; h++) {
        int s   = tid + h * 256;
        int sub = s >> 8;
        int s8  = s & 255;
        int row = s8 >> 2, pos = s8 & 3;
        int q   = pos ^ ((row >> 1) & 3);
        size_t ko = (size_t)(kc + sub * 32 + q * 8);
        GLL(zhiB + (size_t)row * CDIM + ko, &sm.st.ah[sub][row][pos * 8]);
        GLL(zloB + (size_t)row * CDIM + ko, &sm.st.al[sub][row][pos * 8]);
      }
      // cb arrays: 1024 slots of 16B each
#pragma unroll
      for (int h = 0; h < 4; h++) {
        int s   = tid + h * 256;
        int sub = s >> 9;
        int s9  = s & 511;
        int row = s9 >> 2, pos = s9 & 3;
        int q   = pos ^ ((row >> 1) & 3);
        size_t ko = (size_t)(kc + sub * 32 + q * 8);
        GLL(bhB + (size_t)row * CDIM + ko, &sm.st.bh[sub][row][pos * 8]);
        GLL(blB + (size_t)row * CDIM + ko, &sm.st.bl[sub][row][pos * 8]);
      }
      __syncthreads();

      const int pos = kg ^ sw;
#pragma unroll
      for (int sub = 0; sub < 2; sub++) {
        s16x8 zah[2], zal[2], ebh[4], ebl[4];
#pragma unroll
        for (int t = 0; t < 2; t++) {
          zah[t] = *(const s16x8*)&sm.st.ah[sub][wr * 32 + t * 16 + lr][pos * 8];
          zal[t] = *(const s16x8*)&sm.st.al[sub][wr * 32 + t * 16 + lr][pos * 8];
        }
#pragma unroll
        for (int t = 0; t < 4; t++) {
          ebh[t] = *(const s16x8*)&sm.st.bh[sub][wc * 64 + t * 16 + lr][pos * 8];
          ebl[t] = *(const s16x8*)&sm.st.bl[sub][wc * 64 + t * 16 + lr][pos * 8];
        }
#pragma unroll
        for (int tr = 0; tr < 2; tr++)
#pragma unroll
          for (int tc = 0; tc < 4; tc++) {
            acc[tr][tc] = __builtin_amdgcn_mfma_f32_16x16x32_bf16(
                zah[tr], ebh[tc], acc[tr][tc], 0, 0, 0);
            acc[tr][tc] = __builtin_amdgcn_mfma_f32_16x16x32_bf16(
                zah[tr], ebl[tc], acc[tr][tc], 0, 0, 0);
            acc[tr][tc] = __builtin_amdgcn_mfma_f32_16x16x32_bf16(
                zal[tr], ebh[tc], acc[tr][tc], 0, 0, 0);
          }
      }
    }

    // chunk epilogue: screened d = e2 - 2G, fold into lane-local best-2
    float e2c[4];
#pragma unroll
    for (int tc = 0; tc < 4; tc++)
      e2c[tc] = e2[code0 + wc * 64 + tc * 16 + lr];
#pragma unroll
    for (int tr = 0; tr < 2; tr++)
#pragma unroll
      for (int rg = 0; rg < 4; rg++) {
        const int rs = tr * 4 + rg;
#pragma unroll
        for (int tc = 0; tc < 4; tc++) {
          float a = acc[tr][tc][rg];
          float d = e2c[tc] - 2.0f * a;
          int code = code0 + wc * 64 + tc * 16 + lr;
          if (d < bv2[rs]) {
            if (d < bv1[rs]) { bv2[rs] = bv1[rs]; bv1[rs] = d; bi1[rs] = code; }
            else bv2[rs] = d;
          }
        }
      }
  }

  // butterfly best-2 merge across the 16 lanes sharing this row set
#pragma unroll
  for (int rs = 0; rs < 8; rs++) {
#pragma unroll
    for (int m = 1; m <= 8; m <<= 1) {
      float o1 = __shfl_xor(bv1[rs], m);
      float o2 = __shfl_xor(bv2[rs], m);
      int   oi = __shfl_xor(bi1[rs], m);
      float mx = fmaxf(bv1[rs], o1);
      if (o1 < bv1[rs]) { bv1[rs] = o1; bi1[rs] = oi; }
      bv2[rs] = fminf(fminf(bv2[rs], o2), mx);
    }
  }

  __syncthreads();                       // stage mem dead; reuse as RedMem
  if (lr == 0) {
#pragma unroll
    for (int tr = 0; tr < 2; tr++)
#pragma unroll
      for (int rg = 0; rg < 4; rg++) {
        int rs = tr * 4 + rg;
        int r  = wr * 32 + tr * 16 + kg * 4 + rg;
        sm.rd.rv1[r][wc] = bv1[rs];
        sm.rd.rv2[r][wc] = bv2[rs];
        sm.rd.ri1[r][wc] = bi1[rs];
      }
  }
  __syncthreads();
  if (tid < BM) {
    float a1 = sm.rd.rv1[tid][0], b1 = sm.rd.rv1[tid][1];
    float a2 = sm.rd.rv2[tid][0], b2 = sm.rd.rv2[tid][1];
    int   ai = sm.rd.ri1[tid][0], bi = sm.rd.ri1[tid][1];
    float v1 = fminf(a1, b1);
    int   i1 = (b1 < a1) ? bi : ai;
    float v2 = fminf(fminf(a2, b2), fmaxf(a1, b1));
    int n = row0 + tid;
    out_idx[n] = i1;
    if (v2 - v1 <= FBW) {
      int slot = atomicAdd(fb_cnt, 1);
      fb_list[slot] = n;
    }
  }
}

// ---------------------------------------------------------------------------
// bit-exact (numpy semantics) full rescan for flagged rows.
// zrow staged from strided z; codebook side coalesced via cbT in d_ws.
// 4 waves x 64 lanes x 4 codes/lane = 1024 codes; each code is a strictly
// sequential k=0..255 mul-then-add fp32 chain (reference order).
// ---------------------------------------------------------------------------
__global__ __launch_bounds__(256) void fallback_kernel(
    const float* __restrict__ z, const float* __restrict__ cbT,
    const float* __restrict__ z2, const float* __restrict__ e2,
    const int* __restrict__ fb_cnt, const int* __restrict__ fb_list,
    int* __restrict__ out_idx) {
#pragma clang fp contract(off)
  __shared__ float zrow[CDIM];
  __shared__ float rv[4];
  __shared__ int   ri[4];
  const int cnt  = *fb_cnt;
  const int tid  = threadIdx.x;
  const int lane = tid & 63;
  const int w    = tid >> 6;
  for (int q = blockIdx.x; q < cnt; q += gridDim.x) {
    const int n = fb_list[q];
    const int b = n >> 11, t = n & (TT - 1);
    __syncthreads();                       // zrow/rv reuse barrier
    zrow[tid] = z[((size_t)b * CDIM + tid) * TT + t];
    __syncthreads();
    const float z2n = z2[n];
    const int   c0  = w * 256 + lane;      // lane's first code
    const float* ct = cbT + c0;
    float acc0 = 0.f, acc1 = 0.f, acc2 = 0.f, acc3 = 0.f;
    for (int k = 0; k < CDIM; k++) {
      float zk = zrow[k];
      const float* p = ct + (size_t)k * NE;
      acc0 = acc0 + zk * p[0];
      acc1 = acc1 + zk * p[64];
      acc2 = acc2 + zk * p[128];
      acc3 = acc3 + zk * p[192];
    }
    float bv = __builtin_inff(); int bi = 0;
    float dd;
    dd = (z2n + e2[c0 +   0]) - 2.0f * acc0; if (dd < bv) { bv = dd; bi = c0; }
    dd = (z2n + e2[c0 +  64]) - 2.0f * acc1; if (dd < bv) { bv = dd; bi = c0 + 64; }
    dd = (z2n + e2[c0 + 128]) - 2.0f * acc2; if (dd < bv) { bv = dd; bi = c0 + 128; }
    dd = (z2n + e2[c0 + 192]) - 2.0f * acc3; if (dd < bv) { bv = dd; bi = c0 + 192; }
    // wave-level (value, min-index-on-tie) reduce: first-occurrence semantics
#pragma unroll
    for (int m = 1; m < 64; m <<= 1) {
      float ov = __shfl_xor(bv, m);
      int   oi = __shfl_xor(bi, m);
      if (ov < bv || (ov == bv && oi < bi)) { bv = ov; bi = oi; }
    }
    if (lane == 0) { rv[w] = bv; ri[w] = bi; }
    __syncthreads();
    if (tid == 0) {
      float v = rv[0]; int i = ri[0];
#pragma unroll
      for (int x = 1; x < 4; x++)
        if (rv[x] < v || (rv[x] == v && ri[x] < i)) { v = rv[x]; i = ri[x]; }
      out_idx[n] = i;
    }
  }
}

// ---------------------------------------------------------------------------
// Gather z_q, straight-through output fl(z + fl(zq - z)), loss accumulation
// ---------------------------------------------------------------------------
__global__ __launch_bounds__(256) void zq_loss_kernel(
    const float* __restrict__ z, const float* __restrict__ cb,
    const int* __restrict__ idx, float* __restrict__ zq_out,
    double* __restrict__ loss_acc) {
#pragma clang fp contract(off)
  __shared__ double sh[256];
  double local = 0.0;
  int stride = gridDim.x * blockDim.x;
  for (int i = blockIdx.x * blockDim.x + threadIdx.x; i < NELEM; i += stride) {
    int t = i & (TT - 1);
    int b = i >> 19;
    int c = (i >> 11) & (CDIM - 1);
    int n = (b << 11) | t;
    float zq   = cb[(size_t)idx[n] * CDIM + c];
    float zv   = z[i];
    float diff = zq - zv;
    zq_out[i]  = zv + diff;
    float sq   = diff * diff;
    local += (double)sq;
  }
  sh[threadIdx.x] = local;
  __syncthreads();
  for (int s = 128; s > 0; s >>= 1) {
    if (threadIdx.x < s) sh[threadIdx.x] += sh[threadIdx.x + s];
    __syncthreads();
  }
  if (threadIdx.x == 0) atomicAdd(loss_acc, sh[0]);
}

// one-hot (every element written once) + indices output + histogram
__global__ __launch_bounds__(256) void onehot_kernel(
    const int* __restrict__ idx, float* __restrict__ oh,
    float* __restrict__ idx_out, int* __restrict__ cnt) {
  int row  = blockIdx.x * 4 + (threadIdx.x >> 6);
  int lane = threadIdx.x & 63;
  int k    = idx[row];
  if (lane == 0) {
    idx_out[row] = (float)k;
    atomicAdd(&cnt[k], 1);
  }
  float4* dst = (float4*)(oh + (size_t)row * NE);
#pragma unroll
  for (int i = 0; i < 4; i++) {
    int c4   = i * 64 + lane;
    int base = c4 * 4;
    float4 v = {0.f, 0.f, 0.f, 0.f};
    if (k >= base && k < base + 4) ((float*)&v)[k - base] = 1.0f;
    dst[c4] = v;
  }
}

__global__ __launch_bounds__(1024) void finalize_kernel(
    const int* __restrict__ cnt, const double* __restrict__ loss_acc,
    float* __restrict__ out_loss, float* __restrict__ out_perp) {
#pragma clang fp contract(off)
  __shared__ float sh[1024];
  int t = threadIdx.x;
  float em = (float)cnt[t] / 65536.0f;
  sh[t] = em * logf(em + 1e-10f);
  __syncthreads();
  for (int s = 512; s > 0; s >>= 1) {
    if (t < s) sh[t] += sh[t + s];
    __syncthreads();
  }
  if (t == 0) {
    *out_perp = expf(-sh[0]);
    double m  = *loss_acc / (double)NELEM;
    float mf  = (float)m;
    float bt  = 0.25f * mf;
    *out_loss = mf + bt;
  }
}

// ---------------------------------------------------------------------------
extern "C" void kernel_launch(void* const* d_in, const int* in_sizes, int n_in,
                              void* d_out, int out_size, void* d_ws,
                              size_t ws_size, hipStream_t stream) {
  const float* z  = (const float*)d_in[0];
  const float* cb = (const float*)d_in[1];
  float* out = (float*)d_out;

  // workspace layout (total ~1.8 MB; r2 bench proved >= 2.31 MB available)
  int*    ws_idx   = (int*)d_ws;                 // 65536 ints
  int*    ws_cnt   = ws_idx + NROWS;             // 1024 ints
  int*    ws_fbcnt = ws_cnt + NE;                // 1 int
  int*    ws_pad   = ws_fbcnt + 1;               // 1 int (align)
  double* ws_loss  = (double*)(ws_pad + 1);      // 1 double
  float*  ws_e2    = (float*)(ws_loss + 1);      // 1024 floats
  float*  ws_z2    = ws_e2 + NE;                 // 65536 floats
  int*    ws_fbl   = (int*)(ws_z2 + NROWS);      // 65536 ints
  float*  ws_cbT   = (float*)(ws_fbl + NROWS);   // 262144 floats (1 MB)

  // output layout (flat fp32 concat, reference return order)
  float* out_loss = out;
  float* out_zq   = out + 1;
  float* out_perp = out + 1 + (size_t)NELEM;
  float* out_oh   = out + 2 + (size_t)NELEM;
  float* out_idx  = out + 2 + (size_t)NELEM + (size_t)NROWS * NE;

  // bf16-split scratch inside the (not yet written) one-hot output region —
  // EXACTLY the r3/r10-proven 68 MB footprint.
  uintptr_t sc = ((uintptr_t)out_oh + 63) & ~(uintptr_t)63;
  u16*   zhi  = (u16*)sc;
  u16*   zlo  = zhi + (size_t)NROWS * CDIM;
  u16*   cbhi = zlo + (size_t)NROWS * CDIM;
  u16*   cblo = cbhi + (size_t)NE * CDIM;

  hipMemsetAsync(ws_cnt, 0, NE * sizeof(int) + 2 * sizeof(int) + sizeof(double),
                 stream);

  transpose_cb_kernel<<<dim3(NE / 32, CDIM / 32), 256, 0, stream>>>(cb, ws_cbT);
  convert_cb_kernel<<<NE * CDIM / 256, 256, 0, stream>>>(cb, cbhi, cblo);
  convert_z_kernel<<<BB * 512, 256, 0, stream>>>(z, zhi, zlo);
  e2_kernel<<<NE / 256, 256, 0, stream>>>(cb, ws_e2);
  z2_kernel<<<NROWS / 256, 256, 0, stream>>>(z, ws_z2);
  dist_argmin_kernel<<<NROWS / BM, 256, 0, stream>>>(
      zhi, zlo, cbhi, cblo, ws_e2, ws_idx, ws_fbcnt, ws_fbl);
  fallback_kernel<<<2048, 256, 0, stream>>>(z, ws_cbT, ws_z2, ws_e2, ws_fbcnt,
                                            ws_fbl, ws_idx);
  zq_loss_kernel<<<2048, 256, 0, stream>>>(z, cb, ws_idx, out_zq, ws_loss);
  onehot_kernel<<<NROWS / 4, 256, 0, stream>>>(ws_idx, out_oh, out_idx,
                                               ws_cnt);
  finalize_kernel<<<1, 1024, 0, stream>>>(ws_cnt, ws_loss, out_loss, out_perp);
}

// Round 12
// 816.162 us; speedup vs baseline: 1.2300x; 1.2300x over previous
//
#include <hip/hip_runtime.h>

#define BB    32
#define CDIM  256
#define TT    2048
#define NE    1024
#define NROWS (BB * TT)          // 65536
#define NELEM (BB * CDIM * TT)   // 16777216

#define BM   128                 // rows per block (r10-proven tile)
#define NPL  64                  // 8 code-chunks x 8 k-planes of 32

// screening window (r3/r10-proven value): rows with (2nd best - best) <= FBW
// are re-resolved by the bit-exact fallback scan.  2B ~= 1.32e-4 (exact-gap
// quantization 2*ulp(256) + split/order error); 2.5e-4 gives ~1.9x margin.
#define FBW 2.5e-4f

typedef unsigned short u16;
typedef unsigned int   u32;
typedef __attribute__((ext_vector_type(8))) short s16x8;   // 8 bf16
typedef __attribute__((ext_vector_type(4))) float f32x4;

__device__ __forceinline__ u16 f2bf(float f) {
  u32 u = __float_as_uint(f);
  u += 0x7fffu + ((u >> 16) & 1u);     // RNE; no NaN/overflow in our range
  return (u16)(u >> 16);
}

// ---------------------------------------------------------------------------
// numpy pairwise sum of squares over 128 elements (stride in elements).
// fp contract OFF (numpy squares then adds, no FMA).  EXACT path helpers.
// ---------------------------------------------------------------------------
__device__ __forceinline__ float np_sq_sum128(const float* p, int stride) {
#pragma clang fp contract(off)
  float r[8];
#pragma unroll
  for (int j = 0; j < 8; j++) {
    float v = p[(size_t)j * stride];
    r[j] = v * v;
  }
  for (int i = 8; i < 128; i += 8) {
#pragma unroll
    for (int j = 0; j < 8; j++) {
      float v = p[(size_t)(i + j) * stride];
      float s = v * v;
      r[j] += s;
    }
  }
  return ((r[0] + r[1]) + (r[2] + r[3])) + ((r[4] + r[5]) + (r[6] + r[7]));
}

__global__ __launch_bounds__(256) void e2_kernel(const float* __restrict__ cb,
                                                 float* __restrict__ e2) {
#pragma clang fp contract(off)
  int k = blockIdx.x * 256 + threadIdx.x;
  if (k >= NE) return;
  const float* p = cb + (size_t)k * CDIM;
  float h0 = np_sq_sum128(p, 1);
  float h1 = np_sq_sum128(p + 128, 1);
  e2[k] = h0 + h1;
}

__global__ __launch_bounds__(256) void z2_kernel(const float* __restrict__ z,
                                                 float* __restrict__ z2) {
#pragma clang fp contract(off)
  int n = blockIdx.x * 256 + threadIdx.x;
  if (n >= NROWS) return;
  int b = n >> 11;
  int t = n & (TT - 1);
  const float* p = z + (size_t)b * CDIM * TT + t;
  float h0 = np_sq_sum128(p, TT);
  float h1 = np_sq_sum128(p + (size_t)128 * TT, TT);
  z2[n] = h0 + h1;
}

// cb (1024 x 256) -> cbT (256 x 1024) in d_ws, both sides coalesced
__global__ __launch_bounds__(256) void transpose_cb_kernel(
    const float* __restrict__ cb, float* __restrict__ cbT) {
  __shared__ float tile[32][33];
  int tx = threadIdx.x & 31, ty = threadIdx.x >> 5;
  int n0 = blockIdx.x * 32, c0 = blockIdx.y * 32;
#pragma unroll
  for (int i = 0; i < 4; i++)
    tile[ty + 8 * i][tx] = cb[(size_t)(n0 + ty + 8 * i) * CDIM + c0 + tx];
  __syncthreads();
#pragma unroll
  for (int i = 0; i < 4; i++)
    cbT[(size_t)(c0 + ty + 8 * i) * NE + n0 + tx] = tile[tx][ty + 8 * i];
}

// ---------------------------------------------------------------------------
// cb (1024 x 256) fp32 -> cbhi/cblo bf16 (hi + residual), same [code][k] layout
// ---------------------------------------------------------------------------
__global__ __launch_bounds__(256) void convert_cb_kernel(
    const float* __restrict__ cb, u16* __restrict__ cbhi,
    u16* __restrict__ cblo) {
  int i = blockIdx.x * 256 + threadIdx.x;   // grid 1024 -> 262144 elems
  float v  = cb[i];
  u16  h   = f2bf(v);
  float hf = __uint_as_float((u32)h << 16);
  cbhi[i] = h;
  cblo[i] = f2bf(v - hf);
}

// ---------------------------------------------------------------------------
// z (B, C, T) fp32 -> zhi/zlo bf16, row-major [(b,t)][c]   (tiled transpose)
// ---------------------------------------------------------------------------
__global__ __launch_bounds__(256) void convert_z_kernel(
    const float* __restrict__ z, u16* __restrict__ zhi,
    u16* __restrict__ zlo) {
  __shared__ float tile[32][33];
  int bx = blockIdx.x;              // 32 b * 8 c-tiles * 64 t-tiles = 16384
  int b  = bx >> 9;
  int r  = bx & 511;
  int c0 = (r >> 6) << 5;
  int t0 = (r & 63) << 5;
  int tx = threadIdx.x & 31, ty = threadIdx.x >> 5;
#pragma unroll
  for (int i = 0; i < 4; i++) {
    int c = c0 + ty + 8 * i;
    tile[ty + 8 * i][tx] = z[((size_t)b * CDIM + c) * TT + t0 + tx];
  }
  __syncthreads();
#pragma unroll
  for (int i = 0; i < 4; i++) {
    int tl = ty + 8 * i;
    size_t n = (size_t)b * TT + t0 + tl;
    float v  = tile[tx][tl];
    u16  h   = f2bf(v);
    float hf = __uint_as_float((u32)h << 16);
    zhi[n * CDIM + c0 + tx] = h;
    zlo[n * CDIM + c0 + tx] = f2bf(v - hf);
  }
}

// ---------------------------------------------------------------------------
// Distance screen + argmin: bf16-split MFMA GEMM, r10 numerics (BM=128),
// restructured as a 64-plane double-buffered pipeline (T3/T4-minimum):
// per plane: s_barrier -> issue next-plane GLLs -> ds_read+MFMA current ->
// (chunk tail: best-2 fold) -> s_waitcnt vmcnt(0).  GLL flight hides under
// compute; one barrier per plane.
// G = zhi*chi + zhi*clo + zlo*chi; screened d = e2[c] - 2G.
// ---------------------------------------------------------------------------
struct StageMem {                       // 64 KiB (2 x 32 KiB k-plane buffers)
  u16 ah[2][BM][32];                    // zhi  [buf][row][k]
  u16 al[2][BM][32];                    // zlo
  u16 bh[2][128][32];                   // cbhi [buf][code][k]
  u16 bl[2][128][32];                   // cblo
};
struct RedMem {
  float rv1[BM][2];
  float rv2[BM][2];
  int   ri1[BM][2];
};

#define GLL(g, l)                                                            \
  __builtin_amdgcn_global_load_lds(                                          \
      (const __attribute__((address_space(1))) void*)(g),                    \
      (__attribute__((address_space(3))) void*)(l), 16, 0, 0)

__global__ __launch_bounds__(256, 2) void dist_argmin_kernel(
    const u16* __restrict__ zhi, const u16* __restrict__ zlo,
    const u16* __restrict__ cbhi, const u16* __restrict__ cblo,
    const float* __restrict__ e2, int* __restrict__ out_idx,
    int* __restrict__ fb_cnt, int* __restrict__ fb_list) {
  __shared__ union SMem {
    StageMem st;
    RedMem   rd;
  } sm;

  const int tid  = threadIdx.x;
  const int lane = tid & 63;
  const int wid  = tid >> 6;
  const int wr   = wid >> 1;            // wave row (0..1): rows wr*64..
  const int wc   = wid & 1;             // wave col (0..1): codes wc*64..
  const int lr   = lane & 15;           // A-row / B-col within 16x16 tile
  const int kg   = lane >> 4;           // k-group (8 k's each)
  const int row0 = blockIdx.x * BM;
  const int sw   = (lr >> 1) & 3;       // frag-read swizzle (row>>1)&3

  const u16* zhiB = zhi + (size_t)row0 * CDIM;
  const u16* zloB = zlo + (size_t)row0 * CDIM;

  // per-thread staging coordinates (two 16B slots per array per plane)
  const int s0 = tid,        s1 = tid + 256;
  const int r0 = s0 >> 2,    r1 = s1 >> 2;
  const int p0 = s0 & 3,     p1 = s1 & 3;
  const int q0 = p0 ^ ((r0 >> 1) & 3);
  const int q1 = p1 ^ ((r1 >> 1) & 3);

#define STAGE_PLANE(pl, buf)                                                 \
  do {                                                                       \
    const int ch_   = (pl) >> 3;                                             \
    const int kc_   = ((pl) & 7) * 32;                                       \
    const int c0_   = ch_ * 128;                                             \
    const size_t k0_ = (size_t)(kc_ + q0 * 8);                               \
    const size_t k1_ = (size_t)(kc_ + q1 * 8);                               \
    GLL(zhiB + (size_t)r0 * CDIM + k0_, &sm.st.ah[buf][r0][p0 * 8]);         \
    GLL(zhiB + (size_t)r1 * CDIM + k1_, &sm.st.ah[buf][r1][p1 * 8]);         \
    GLL(zloB + (size_t)r0 * CDIM + k0_, &sm.st.al[buf][r0][p0 * 8]);         \
    GLL(zloB + (size_t)r1 * CDIM + k1_, &sm.st.al[buf][r1][p1 * 8]);         \
    GLL(cbhi + (size_t)(c0_ + r0) * CDIM + k0_, &sm.st.bh[buf][r0][p0 * 8]); \
    GLL(cbhi + (size_t)(c0_ + r1) * CDIM + k1_, &sm.st.bh[buf][r1][p1 * 8]); \
    GLL(cblo + (size_t)(c0_ + r0) * CDIM + k0_, &sm.st.bl[buf][r0][p0 * 8]); \
    GLL(cblo + (size_t)(c0_ + r1) * CDIM + k1_, &sm.st.bl[buf][r1][p1 * 8]); \
  } while (0)

  float bv1[16], bv2[16];
  int   bi1[16];
#pragma unroll
  for (int i = 0; i < 16; i++) {
    bv1[i] = __builtin_inff(); bv2[i] = __builtin_inff(); bi1[i] = 0;
  }

  f32x4 acc[4][4];
#pragma unroll
  for (int a = 0; a < 4; a++)
#pragma unroll
    for (int b = 0; b < 4; b++) acc[a][b] = (f32x4){0.f, 0.f, 0.f, 0.f};

  int cur = 0;
  STAGE_PLANE(0, 0);
  asm volatile("s_waitcnt vmcnt(0)" ::: "memory");
  __builtin_amdgcn_sched_barrier(0);

  const int pos = kg ^ sw;

  for (int t = 0; t < NPL; ++t) {
    __builtin_amdgcn_s_barrier();        // plane t staged by ALL waves
    __builtin_amdgcn_sched_barrier(0);   // no hoisting of reads above barrier

    if (t < NPL - 1) STAGE_PLANE(t + 1, cur ^ 1);

    s16x8 zah[4], zal[4], ebh[4], ebl[4];
#pragma unroll
    for (int t4 = 0; t4 < 4; t4++) {
      zah[t4] = *(const s16x8*)&sm.st.ah[cur][wr * 64 + t4 * 16 + lr][pos * 8];
      zal[t4] = *(const s16x8*)&sm.st.al[cur][wr * 64 + t4 * 16 + lr][pos * 8];
      ebh[t4] = *(const s16x8*)&sm.st.bh[cur][wc * 64 + t4 * 16 + lr][pos * 8];
      ebl[t4] = *(const s16x8*)&sm.st.bl[cur][wc * 64 + t4 * 16 + lr][pos * 8];
    }
#pragma unroll
    for (int tr = 0; tr < 4; tr++)
#pragma unroll
      for (int tc = 0; tc < 4; tc++) {
        acc[tr][tc] = __builtin_amdgcn_mfma_f32_16x16x32_bf16(
            zah[tr], ebh[tc], acc[tr][tc], 0, 0, 0);
        acc[tr][tc] = __builtin_amdgcn_mfma_f32_16x16x32_bf16(
            zah[tr], ebl[tc], acc[tr][tc], 0, 0, 0);
        acc[tr][tc] = __builtin_amdgcn_mfma_f32_16x16x32_bf16(
            zal[tr], ebh[tc], acc[tr][tc], 0, 0, 0);
      }

    if ((t & 7) == 7) {                  // chunk tail: fold + reset acc
      const int code0 = (t >> 3) * 128;
      float e2c[4];
#pragma unroll
      for (int tc = 0; tc < 4; tc++)
        e2c[tc] = e2[code0 + wc * 64 + tc * 16 + lr];
#pragma unroll
      for (int tr = 0; tr < 4; tr++)
#pragma unroll
        for (int rg = 0; rg < 4; rg++) {
          const int rs = tr * 4 + rg;
#pragma unroll
          for (int tc = 0; tc < 4; tc++) {
            float a = acc[tr][tc][rg];
            float d = e2c[tc] - 2.0f * a;
            int code = code0 + wc * 64 + tc * 16 + lr;
            if (d < bv2[rs]) {
              if (d < bv1[rs]) { bv2[rs] = bv1[rs]; bv1[rs] = d; bi1[rs] = code; }
              else bv2[rs] = d;
            }
          }
        }
#pragma unroll
      for (int a = 0; a < 4; a++)
#pragma unroll
        for (int b = 0; b < 4; b++) acc[a][b] = (f32x4){0.f, 0.f, 0.f, 0.f};
    }

    asm volatile("s_waitcnt vmcnt(0)" ::: "memory");  // next plane landed (mine)
    __builtin_amdgcn_sched_barrier(0);
    cur ^= 1;
  }
#undef STAGE_PLANE

  // butterfly best-2 merge across the 16 lanes sharing this row set
#pragma unroll
  for (int rs = 0; rs < 16; rs++) {
#pragma unroll
    for (int m = 1; m <= 8; m <<= 1) {
      float o1 = __shfl_xor(bv1[rs], m);
      float o2 = __shfl_xor(bv2[rs], m);
      int   oi = __shfl_xor(bi1[rs], m);
      float mx = fmaxf(bv1[rs], o1);
      if (o1 < bv1[rs]) { bv1[rs] = o1; bi1[rs] = oi; }
      bv2[rs] = fminf(fminf(bv2[rs], o2), mx);
    }
  }

  __syncthreads();                       // stage mem dead; reuse as RedMem
  if (lr == 0) {
#pragma unroll
    for (int tr = 0; tr < 4; tr++)
#pragma unroll
      for (int rg = 0; rg < 4; rg++) {
        int rs = tr * 4 + rg;
        int r  = wr * 64 + tr * 16 + kg * 4 + rg;
        sm.rd.rv1[r][wc] = bv1[rs];
        sm.rd.rv2[r][wc] = bv2[rs];
        sm.rd.ri1[r][wc] = bi1[rs];
      }
  }
  __syncthreads();
  if (tid < BM) {
    float a1 = sm.rd.rv1[tid][0], b1 = sm.rd.rv1[tid][1];
    float a2 = sm.rd.rv2[tid][0], b2 = sm.rd.rv2[tid][1];
    int   ai = sm.rd.ri1[tid][0], bi = sm.rd.ri1[tid][1];
    float v1 = fminf(a1, b1);
    int   i1 = (b1 < a1) ? bi : ai;
    float v2 = fminf(fminf(a2, b2), fmaxf(a1, b1));
    int n = row0 + tid;
    out_idx[n] = i1;
    if (v2 - v1 <= FBW) {
      int slot = atomicAdd(fb_cnt, 1);
      fb_list[slot] = n;
    }
  }
}

// ---------------------------------------------------------------------------
// bit-exact (numpy semantics) full rescan for flagged rows.
// zrow staged from strided z; codebook side coalesced via cbT in d_ws.
// 4 waves x 64 lanes x 4 codes/lane = 1024 codes; each code is a strictly
// sequential k=0..255 mul-then-add fp32 chain (reference order).
// ---------------------------------------------------------------------------
__global__ __launch_bounds__(256) void fallback_kernel(
    const float* __restrict__ z, const float* __restrict__ cbT,
    const float* __restrict__ z2, const float* __restrict__ e2,
    const int* __restrict__ fb_cnt, const int* __restrict__ fb_list,
    int* __restrict__ out_idx) {
#pragma clang fp contract(off)
  __shared__ float zrow[CDIM];
  __shared__ float rv[4];
  __shared__ int   ri[4];
  const int cnt  = *fb_cnt;
  const int tid  = threadIdx.x;
  const int lane = tid & 63;
  const int w    = tid >> 6;
  for (int q = blockIdx.x; q < cnt; q += gridDim.x) {
    const int n = fb_list[q];
    const int b = n >> 11, t = n & (TT - 1);
    __syncthreads();                       // zrow/rv reuse barrier
    zrow[tid] = z[((size_t)b * CDIM + tid) * TT + t];
    __syncthreads();
    const float z2n = z2[n];
    const int   c0  = w * 256 + lane;      // lane's first code
    const float* ct = cbT + c0;
    float acc0 = 0.f, acc1 = 0.f, acc2 = 0.f, acc3 = 0.f;
    for (int k = 0; k < CDIM; k++) {
      float zk = zrow[k];
      const float* p = ct + (size_t)k * NE;
      acc0 = acc0 + zk * p[0];
      acc1 = acc1 + zk * p[64];
      acc2 = acc2 + zk * p[128];
      acc3 = acc3 + zk * p[192];
    }
    float bv = __builtin_inff(); int bi = 0;
    float dd;
    dd = (z2n + e2[c0 +   0]) - 2.0f * acc0; if (dd < bv) { bv = dd; bi = c0; }
    dd = (z2n + e2[c0 +  64]) - 2.0f * acc1; if (dd < bv) { bv = dd; bi = c0 + 64; }
    dd = (z2n + e2[c0 + 128]) - 2.0f * acc2; if (dd < bv) { bv = dd; bi = c0 + 128; }
    dd = (z2n + e2[c0 + 192]) - 2.0f * acc3; if (dd < bv) { bv = dd; bi = c0 + 192; }
    // wave-level (value, min-index-on-tie) reduce: first-occurrence semantics
#pragma unroll
    for (int m = 1; m < 64; m <<= 1) {
      float ov = __shfl_xor(bv, m);
      int   oi = __shfl_xor(bi, m);
      if (ov < bv || (ov == bv && oi < bi)) { bv = ov; bi = oi; }
    }
    if (lane == 0) { rv[w] = bv; ri[w] = bi; }
    __syncthreads();
    if (tid == 0) {
      float v = rv[0]; int i = ri[0];
#pragma unroll
      for (int x = 1; x < 4; x++)
        if (rv[x] < v || (rv[x] == v && ri[x] < i)) { v = rv[x]; i = ri[x]; }
      out_idx[n] = i;
    }
  }
}

// ---------------------------------------------------------------------------
// Gather z_q, straight-through output fl(z + fl(zq - z)), loss accumulation
// ---------------------------------------------------------------------------
__global__ __launch_bounds__(256) void zq_loss_kernel(
    const float* __restrict__ z, const float* __restrict__ cb,
    const int* __restrict__ idx, float* __restrict__ zq_out,
    double* __restrict__ loss_acc) {
#pragma clang fp contract(off)
  __shared__ double sh[256];
  double local = 0.0;
  int stride = gridDim.x * blockDim.x;
  for (int i = blockIdx.x * blockDim.x + threadIdx.x; i < NELEM; i += stride) {
    int t = i & (TT - 1);
    int b = i >> 19;
    int c = (i >> 11) & (CDIM - 1);
    int n = (b << 11) | t;
    float zq   = cb[(size_t)idx[n] * CDIM + c];
    float zv   = z[i];
    float diff = zq - zv;
    zq_out[i]  = zv + diff;
    float sq   = diff * diff;
    local += (double)sq;
  }
  sh[threadIdx.x] = local;
  __syncthreads();
  for (int s = 128; s > 0; s >>= 1) {
    if (threadIdx.x < s) sh[threadIdx.x] += sh[threadIdx.x + s];
    __syncthreads();
  }
  if (threadIdx.x == 0) atomicAdd(loss_acc, sh[0]);
}

// one-hot (every element written once) + indices output + histogram
__global__ __launch_bounds__(256) void onehot_kernel(
    const int* __restrict__ idx, float* __restrict__ oh,
    float* __restrict__ idx_out, int* __restrict__ cnt) {
  int row  = blockIdx.x * 4 + (threadIdx.x >> 6);
  int lane = threadIdx.x & 63;
  int k    = idx[row];
  if (lane == 0) {
    idx_out[row] = (float)k;
    atomicAdd(&cnt[k], 1);
  }
  float4* dst = (float4*)(oh + (size_t)row * NE);
#pragma unroll
  for (int i = 0; i < 4; i++) {
    int c4   = i * 64 + lane;
    int base = c4 * 4;
    float4 v = {0.f, 0.f, 0.f, 0.f};
    if (k >= base && k < base + 4) ((float*)&v)[k - base] = 1.0f;
    dst[c4] = v;
  }
}

__global__ __launch_bounds__(1024) void finalize_kernel(
    const int* __restrict__ cnt, const double* __restrict__ loss_acc,
    float* __restrict__ out_loss, float* __restrict__ out_perp) {
#pragma clang fp contract(off)
  __shared__ float sh[1024];
  int t = threadIdx.x;
  float em = (float)cnt[t] / 65536.0f;
  sh[t] = em * logf(em + 1e-10f);
  __syncthreads();
  for (int s = 512; s > 0; s >>= 1) {
    if (t < s) sh[t] += sh[t + s];
    __syncthreads();
  }
  if (t == 0) {
    *out_perp = expf(-sh[0]);
    double m  = *loss_acc / (double)NELEM;
    float mf  = (float)m;
    float bt  = 0.25f * mf;
    *out_loss = mf + bt;
  }
}

// ---------------------------------------------------------------------------
extern "C" void kernel_launch(void* const* d_in, const int* in_sizes, int n_in,
                              void* d_out, int out_size, void* d_ws,
                              size_t ws_size, hipStream_t stream) {
  const float* z  = (const float*)d_in[0];
  const float* cb = (const float*)d_in[1];
  float* out = (float*)d_out;

  // workspace layout (total ~1.8 MB; r2 bench proved >= 2.31 MB available)
  int*    ws_idx   = (int*)d_ws;                 // 65536 ints
  int*    ws_cnt   = ws_idx + NROWS;             // 1024 ints
  int*    ws_fbcnt = ws_cnt + NE;                // 1 int
  int*    ws_pad   = ws_fbcnt + 1;               // 1 int (align)
  double* ws_loss  = (double*)(ws_pad + 1);      // 1 double
  float*  ws_e2    = (float*)(ws_loss + 1);      // 1024 floats
  float*  ws_z2    = ws_e2 + NE;                 // 65536 floats
  int*    ws_fbl   = (int*)(ws_z2 + NROWS);      // 65536 ints
  float*  ws_cbT   = (float*)(ws_fbl + NROWS);   // 262144 floats (1 MB)

  // output layout (flat fp32 concat, reference return order)
  float* out_loss = out;
  float* out_zq   = out + 1;
  float* out_perp = out + 1 + (size_t)NELEM;
  float* out_oh   = out + 2 + (size_t)NELEM;
  float* out_idx  = out + 2 + (size_t)NELEM + (size_t)NROWS * NE;

  // bf16-split scratch inside the (not yet written) one-hot output region —
  // EXACTLY the r3/r10-proven 68 MB footprint.
  uintptr_t sc = ((uintptr_t)out_oh + 63) & ~(uintptr_t)63;
  u16*   zhi  = (u16*)sc;
  u16*   zlo  = zhi + (size_t)NROWS * CDIM;
  u16*   cbhi = zlo + (size_t)NROWS * CDIM;
  u16*   cblo = cbhi + (size_t)NE * CDIM;

  hipMemsetAsync(ws_cnt, 0, NE * sizeof(int) + 2 * sizeof(int) + sizeof(double),
                 stream);

  transpose_cb_kernel<<<dim3(NE / 32, CDIM / 32), 256, 0, stream>>>(cb, ws_cbT);
  convert_cb_kernel<<<NE * CDIM / 256, 256, 0, stream>>>(cb, cbhi, cblo);
  convert_z_kernel<<<BB * 512, 256, 0, stream>>>(z, zhi, zlo);
  e2_kernel<<<NE / 256, 256, 0, stream>>>(cb, ws_e2);
  z2_kernel<<<NROWS / 256, 256, 0, stream>>>(z, ws_z2);
  dist_argmin_kernel<<<NROWS / BM, 256, 0, stream>>>(
      zhi, zlo, cbhi, cblo, ws_e2, ws_idx, ws_fbcnt, ws_fbl);
  fallback_kernel<<<2048, 256, 0, stream>>>(z, ws_cbT, ws_z2, ws_e2, ws_fbcnt,
                                            ws_fbl, ws_idx);
  zq_loss_kernel<<<2048, 256, 0, stream>>>(z, cb, ws_idx, out_zq, ws_loss);
  onehot_kernel<<<NROWS / 4, 256, 0, stream>>>(ws_idx, out_oh, out_idx,
                                               ws_cnt);
  finalize_kernel<<<1, 1024, 0, stream>>>(ws_cnt, ws_loss, out_loss, out_perp);
}